// Round 2
// baseline (1123.084 us; speedup 1.0000x reference)
//
#include <hip/hip_runtime.h>

// AttentionDecoder: embed -> LSTM(64 steps) -> dot attention -> vocab projection
// B=32 TD=TE=64 V=32000 D=H=512.
// I/O dtypes: ALL float tensors fp32 (per reference); xs int32. Outputs fp32.
// Internally: convert to bf16 at staging (RNE), MFMA 16x16x32_bf16, fp32 accum.
//
// d_out layout (fp32 elems): logits[32][64][32000] | hT[32][512] | cT[32][512] | attn[32][64][64]
// ws layout: xpb bf16[2048][2048] | feat bf16[2048][1024] | hbuf bf16[2][32][512] | cnt u32

typedef unsigned short u16;
typedef unsigned int u32;
typedef __bf16 bf16x8 __attribute__((ext_vector_type(8)));
typedef float f32x4 __attribute__((ext_vector_type(4)));
typedef u32 u32x4 __attribute__((ext_vector_type(4)));

__device__ __forceinline__ float bf2f(u16 u){ u32 x = ((u32)u)<<16; return __builtin_bit_cast(float, x); }
__device__ __forceinline__ u16 f2bf(float f){ u32 x = __builtin_bit_cast(u32, f); x += 0x7FFFu + ((x>>16)&1u); return (u16)(x>>16); }
__device__ __forceinline__ u32 pk2(float a, float b){ return (u32)f2bf(a) | ((u32)f2bf(b)<<16); }
__device__ __forceinline__ u32x4 pk8(const float* p){
  f32x4 lo = *(const f32x4*)p, hi = *(const f32x4*)(p+4);
  u32x4 r; r[0]=pk2(lo[0],lo[1]); r[1]=pk2(lo[2],lo[3]); r[2]=pk2(hi[0],hi[1]); r[3]=pk2(hi[2],hi[3]);
  return r;
}

__device__ __forceinline__ f32x4 mfma16(u32x4 a, u32x4 b, f32x4 c){
  return __builtin_amdgcn_mfma_f32_16x16x32_bf16(
      __builtin_bit_cast(bf16x8, a), __builtin_bit_cast(bf16x8, b), c, 0, 0, 0);
}

__device__ __forceinline__ void gld16(const void* g, void* l){
  __builtin_amdgcn_global_load_lds(
      (__attribute__((address_space(1))) void*)(void*)g,
      (__attribute__((address_space(3))) void*)l, 16, 0, 0);
}

__device__ __forceinline__ float sigm(float x){ x = fminf(fmaxf(x,-30.f),30.f); return 1.f/(1.f+__expf(-x)); }
__device__ __forceinline__ float tanh_ap(float x){ float xc = fminf(fmaxf(x,-15.f),15.f); float e = __expf(-2.f*xc); return (1.f-e)/(1.f+e); }

// ---- init: h0 fp32 -> hbuf[1] bf16; zero the barrier counter ----
__global__ void k_init(const float* __restrict__ h0, u16* __restrict__ hbuf1, u32* __restrict__ cnt){
  int i = blockIdx.x*256 + threadIdx.x;
  hbuf1[i] = f2bf(h0[i]);
  if (i==0) *cnt = 0u;
}

// ---------------- Kernel 1: xp = embed_W[xs] @ W_ih^T + (b_ih+b_hh), bf16 out ----------------
__global__ __launch_bounds__(256) void k_xp(const int* __restrict__ xs,
    const float* __restrict__ embW, const float* __restrict__ Wih,
    const float* __restrict__ bih, const float* __restrict__ bhh,
    u16* __restrict__ xpb)
{
  __shared__ u16 sm[16384];           // As[128][64] | Bs[128][64] (bf16)
  u16* As = sm; u16* Bs = sm + 8192;
  const int tid = threadIdx.x;
  const int m0 = blockIdx.x*128, n0 = blockIdx.y*128;
  const int wave = tid>>6, lane = tid&63, quad = lane>>4, lr = lane&15;
  const int wm = wave>>1, wn = wave&1;
  const int rbase = tid>>3, cb = (tid&7)*8;   // 8 floats per lane per row-chunk
  int tok[4];
  #pragma unroll
  for (int i=0;i<4;i++) tok[i] = xs[m0 + i*32 + rbase];
  f32x4 acc[4][4];
  #pragma unroll
  for (int i=0;i<4;i++)
    #pragma unroll
    for (int j=0;j<4;j++) acc[i][j] = (f32x4){0.f,0.f,0.f,0.f};

  for (int kb=0; kb<512; kb+=64){
    #pragma unroll
    for (int i=0;i<4;i++)
      *(u32x4*)(As + i*2048 + tid*8) = pk8(embW + (long)tok[i]*512 + kb + cb);
    #pragma unroll
    for (int i=0;i<4;i++)
      *(u32x4*)(Bs + i*2048 + tid*8) = pk8(Wih + (long)(n0 + i*32 + rbase)*512 + kb + cb);
    __syncthreads();
    #pragma unroll
    for (int k0=0;k0<64;k0+=32){
      u32x4 bf[4];
      #pragma unroll
      for (int j=0;j<4;j++) bf[j] = *(const u32x4*)(Bs + (wn*64 + j*16 + lr)*64 + k0 + quad*8);
      #pragma unroll
      for (int i=0;i<4;i++){
        u32x4 af = *(const u32x4*)(As + (wm*64 + i*16 + lr)*64 + k0 + quad*8);
        #pragma unroll
        for (int j=0;j<4;j++) acc[i][j] = mfma16(af, bf[j], acc[i][j]);
      }
    }
    __syncthreads();
  }
  float bias[4];
  #pragma unroll
  for (int j=0;j<4;j++){ int col = n0 + wn*64 + j*16 + lr; bias[j] = bih[col] + bhh[col]; }
  #pragma unroll
  for (int i=0;i<4;i++)
    #pragma unroll
    for (int j=0;j<4;j++){
      int row = m0 + wm*64 + i*16 + quad*4;
      int col = n0 + wn*64 + j*16 + lr;
      #pragma unroll
      for (int r=0;r<4;r++) xpb[(long)(row+r)*2048 + col] = f2bf(acc[i][j][r] + bias[j]);
    }
}

// ---------------- Kernel 2: persistent LSTM, 32 WGs, device-scope spin barrier per step ----------------
// WG w owns h-cols [w*16, w*16+16); wave q computes gate q; W_hh frags register-resident.
__global__ __launch_bounds__(256) void k_lstm(const u16* __restrict__ xpb,
    const float* __restrict__ c0, const float* __restrict__ Whh,
    u16* __restrict__ feat, u16* __restrict__ hbuf, u32* __restrict__ cnt,
    float* __restrict__ outH, float* __restrict__ outC)
{
  __shared__ u16 hS[16384];           // h staged [32][512] bf16
  __shared__ float gacc[4][32][16];   // gate pre-activations
  const int tid = threadIdx.x, w = blockIdx.x;
  const int wave = tid>>6, lane = tid&63, quad = lane>>4, lr = lane&15;
  const int cbase = w*16;

  u32x4 bfrag[16];                    // W_hh B-fragments (fp32 -> bf16 once)
  const float* wrow = Whh + (long)(wave*512 + cbase + lr)*512;
  #pragma unroll
  for (int kit=0;kit<16;kit++) bfrag[kit] = pk8(wrow + kit*32 + quad*8);

  float cst[2]; int bb[2], ccx[2];
  #pragma unroll
  for (int j=0;j<2;j++){ int f = tid*2+j; bb[j] = f>>4; ccx[j] = f&15;
    cst[j] = c0[bb[j]*512 + cbase + ccx[j]]; }

  for (int t=0;t<64;t++){
    if (t>0){
      if (tid==0){
        while (__hip_atomic_load(cnt, __ATOMIC_RELAXED, __HIP_MEMORY_SCOPE_AGENT) < 32u*(u32)t)
          __builtin_amdgcn_s_sleep(2);
      }
      __syncthreads();
      __builtin_amdgcn_fence(__ATOMIC_ACQUIRE, "agent");
    }
    const u16* src = hbuf + (((t+1)&1))*16384;   // t=0 -> buffer 1 (h0, from k_init)
    #pragma unroll
    for (int i=0;i<8;i++)
      gld16(src + i*2048 + tid*8, hS + i*2048 + tid*8);
    float xpv[4][2];
    #pragma unroll
    for (int j=0;j<2;j++){
      long toff = (long)(bb[j]*64 + t)*2048;
      #pragma unroll
      for (int q=0;q<4;q++) xpv[q][j] = bf2f(xpb[toff + q*512 + cbase + ccx[j]]);
    }
    __syncthreads();

    f32x4 acc0 = {0.f,0.f,0.f,0.f}, acc1 = {0.f,0.f,0.f,0.f};
    #pragma unroll
    for (int kit=0;kit<16;kit++){
      u32x4 a0 = *(const u32x4*)(hS + lr*512 + kit*32 + quad*8);
      u32x4 a1 = *(const u32x4*)(hS + (16+lr)*512 + kit*32 + quad*8);
      acc0 = mfma16(a0, bfrag[kit], acc0);
      acc1 = mfma16(a1, bfrag[kit], acc1);
    }
    #pragma unroll
    for (int r=0;r<4;r++){
      gacc[wave][quad*4+r][lr]    = acc0[r];
      gacc[wave][16+quad*4+r][lr] = acc1[r];
    }
    __syncthreads();

    #pragma unroll
    for (int j=0;j<2;j++){
      float gi = gacc[0][bb[j]][ccx[j]] + xpv[0][j];
      float gf = gacc[1][bb[j]][ccx[j]] + xpv[1][j];
      float gg = gacc[2][bb[j]][ccx[j]] + xpv[2][j];
      float go = gacc[3][bb[j]][ccx[j]] + xpv[3][j];
      float cn = sigm(gf)*cst[j] + sigm(gi)*tanh_ap(gg);
      cst[j] = cn;
      float h = sigm(go)*tanh_ap(cn);
      feat[(long)(bb[j]*64 + t)*1024 + cbase + ccx[j]] = f2bf(h);
      if (t < 63) hbuf[(t&1)*16384 + bb[j]*512 + cbase + ccx[j]] = f2bf(h);
      else { outH[bb[j]*512 + cbase + ccx[j]] = h;
             outC[bb[j]*512 + cbase + ccx[j]] = cn; }
    }
    if (t < 63){
      __builtin_amdgcn_fence(__ATOMIC_RELEASE, "agent");
      __syncthreads();
      if (tid==0) __hip_atomic_fetch_add(cnt, 1u, __ATOMIC_RELEASE, __HIP_MEMORY_SCOPE_AGENT);
    }
  }
}

// ---------------- Kernel 3: per batch: s=hs@out^T, softmax(e), ctx=attn^T@hs ----------------
__global__ __launch_bounds__(256) void k_attn(const float* __restrict__ hs,
    u16* __restrict__ feat, float* __restrict__ attnOut)
{
  __shared__ u16 stg[16384];      // 32 KB: hsS[64][256] (phase1) then hsT[256][64] (phase3)
  __shared__ float sS[4096];      // 16 KB
  __shared__ u16 aT[4096];        // 8 KB: attn^T [t][e] bf16
  __shared__ float red[8][64];    // 2 KB
  const int tid = threadIdx.x, b = blockIdx.x;
  const int wave = tid>>6, lane = tid&63, quad = lane>>4, lr = lane&15;
  const float* hsb = hs + (long)b*32768;

  // Phase 1: S[e][t] = sum_h hs[e][h]*out[t][h], h in two 256-halves staged to LDS bf16
  f32x4 sacc[4];
  #pragma unroll
  for (int j=0;j<4;j++) sacc[j] = (f32x4){0.f,0.f,0.f,0.f};
  for (int kk=0; kk<2; kk++){
    int row = tid>>2, cc0 = (tid&3)*64;
    #pragma unroll
    for (int c8=0; c8<8; c8++)
      *(u32x4*)(stg + row*256 + cc0 + c8*8) = pk8(hsb + (long)row*512 + kk*256 + cc0 + c8*8);
    __syncthreads();
    for (int kit=0; kit<8; kit++){
      u32x4 af = *(const u32x4*)(stg + (wave*16 + lr)*256 + kit*32 + quad*8);
      #pragma unroll
      for (int j=0;j<4;j++){
        u32x4 bfv = *(const u32x4*)(feat + (long)(b*64 + j*16 + lr)*1024 + kk*256 + kit*32 + quad*8);
        sacc[j] = mfma16(af, bfv, sacc[j]);
      }
    }
    __syncthreads();
  }
  #pragma unroll
  for (int j=0;j<4;j++)
    #pragma unroll
    for (int r=0;r<4;r++)
      sS[(wave*16 + quad*4 + r)*64 + j*16 + lr] = sacc[j][r];
  __syncthreads();

  // Phase 2: softmax over e (rows) per column t; write attn fp32
  {
    int t = tid&63, qtr = tid>>6;
    float m = -1e30f;
    for (int e=qtr*16; e<qtr*16+16; e++) m = fmaxf(m, sS[e*64+t]);
    red[qtr][t] = m;
    __syncthreads();
    m = fmaxf(fmaxf(red[0][t],red[1][t]), fmaxf(red[2][t],red[3][t]));
    float sum = 0.f;
    for (int e=qtr*16; e<qtr*16+16; e++) sum += __expf(sS[e*64+t]-m);
    red[4+qtr][t] = sum;
    __syncthreads();
    float inv = 1.f/(red[4][t]+red[5][t]+red[6][t]+red[7][t]);
    for (int e=qtr*16; e<qtr*16+16; e++){
      float wgt = __expf(sS[e*64+t]-m)*inv;
      aT[t*64+e] = f2bf(wgt);
      attnOut[b*4096 + e*64 + t] = wgt;
    }
  }
  __syncthreads();

  // Phase 3: ctx[t][h] = sum_e attn[e][t]*hs[e][h], via LDS-transposed bf16 hs
  for (int hh=0; hh<2; hh++){
    #pragma unroll
    for (int it=0; it<8; it++){
      int g = tid*8 + it, e = g>>5, hb = g&31;
      const float* p = hsb + (long)e*512 + hh*256 + hb*8;
      f32x4 lo = *(const f32x4*)p, hi = *(const f32x4*)(p+4);
      stg[(hb*8+0)*64 + e] = f2bf(lo[0]);
      stg[(hb*8+1)*64 + e] = f2bf(lo[1]);
      stg[(hb*8+2)*64 + e] = f2bf(lo[2]);
      stg[(hb*8+3)*64 + e] = f2bf(lo[3]);
      stg[(hb*8+4)*64 + e] = f2bf(hi[0]);
      stg[(hb*8+5)*64 + e] = f2bf(hi[1]);
      stg[(hb*8+6)*64 + e] = f2bf(hi[2]);
      stg[(hb*8+7)*64 + e] = f2bf(hi[3]);
    }
    __syncthreads();
    u32x4 a0 = *(const u32x4*)(aT + (wave*16+lr)*64 + quad*8);
    u32x4 a1 = *(const u32x4*)(aT + (wave*16+lr)*64 + 32 + quad*8);
    for (int hn=0; hn<16; hn++){
      f32x4 c = {0.f,0.f,0.f,0.f};
      u32x4 b0 = *(const u32x4*)(stg + (hn*16+lr)*64 + quad*8);
      u32x4 b1 = *(const u32x4*)(stg + (hn*16+lr)*64 + 32 + quad*8);
      c = mfma16(a0, b0, c);
      c = mfma16(a1, b1, c);
      int hcol = hh*256 + hn*16 + lr;
      #pragma unroll
      for (int r=0;r<4;r++){
        int t = wave*16 + quad*4 + r;
        feat[(long)(b*64 + t)*1024 + 512 + hcol] = f2bf(c[r]);
      }
    }
    __syncthreads();
  }
}

// ---------------- Kernel 4: logits = feat @ aff_W^T + aff_b, fp32 out ----------------
__global__ __launch_bounds__(256) void k_logits(const u16* __restrict__ feat,
    const float* __restrict__ affW, const float* __restrict__ affb, float* __restrict__ outL)
{
  __shared__ u16 sm[16384];
  u16* As = sm; u16* Bs = sm + 8192;
  const int tid = threadIdx.x;
  const int m0 = blockIdx.x*128, n0 = blockIdx.y*128;
  const int wave = tid>>6, lane = tid&63, quad = lane>>4, lr = lane&15;
  const int wm = wave>>1, wn = wave&1;
  const int rbase = tid>>3, cb = (tid&7)*8;
  f32x4 acc[4][4];
  #pragma unroll
  for (int i=0;i<4;i++)
    #pragma unroll
    for (int j=0;j<4;j++) acc[i][j] = (f32x4){0.f,0.f,0.f,0.f};

  for (int kb=0; kb<1024; kb+=64){
    #pragma unroll
    for (int i=0;i<4;i++)
      gld16(feat + (long)(m0 + i*32 + rbase)*1024 + kb + cb, As + i*2048 + tid*8);
    #pragma unroll
    for (int i=0;i<4;i++)
      *(u32x4*)(Bs + i*2048 + tid*8) = pk8(affW + (long)(n0 + i*32 + rbase)*1024 + kb + cb);
    __syncthreads();
    #pragma unroll
    for (int k0=0;k0<64;k0+=32){
      u32x4 bf[4];
      #pragma unroll
      for (int j=0;j<4;j++) bf[j] = *(const u32x4*)(Bs + (wn*64 + j*16 + lr)*64 + k0 + quad*8);
      #pragma unroll
      for (int i=0;i<4;i++){
        u32x4 af = *(const u32x4*)(As + (wm*64 + i*16 + lr)*64 + k0 + quad*8);
        #pragma unroll
        for (int j=0;j<4;j++) acc[i][j] = mfma16(af, bf[j], acc[i][j]);
      }
    }
    __syncthreads();
  }
  float bias[4];
  #pragma unroll
  for (int j=0;j<4;j++) bias[j] = affb[n0 + wn*64 + j*16 + lr];
  #pragma unroll
  for (int i=0;i<4;i++)
    #pragma unroll
    for (int j=0;j<4;j++){
      int row = m0 + wm*64 + i*16 + quad*4;
      int col = n0 + wn*64 + j*16 + lr;
      #pragma unroll
      for (int r=0;r<4;r++) outL[(long)(row+r)*32000 + col] = acc[i][j][r] + bias[j];
    }
}

extern "C" void kernel_launch(void* const* d_in, const int* in_sizes, int n_in,
                              void* d_out, int out_size, void* d_ws, size_t ws_size,
                              hipStream_t stream) {
  const int*   xs   = (const int*)d_in[0];
  const float* hs   = (const float*)d_in[1];
  const float* h0   = (const float*)d_in[2];
  const float* c0   = (const float*)d_in[3];
  const float* embW = (const float*)d_in[4];
  const float* Wih  = (const float*)d_in[5];
  const float* Whh  = (const float*)d_in[6];
  const float* bih  = (const float*)d_in[7];
  const float* bhh  = (const float*)d_in[8];
  const float* affW = (const float*)d_in[9];
  const float* affb = (const float*)d_in[10];
  float* out = (float*)d_out;

  char* ws = (char*)d_ws;
  u16* xpb  = (u16*)ws;                             //  8,388,608 B
  u16* feat = (u16*)(ws + 8388608);                 //  4,194,304 B
  u16* hbuf = (u16*)(ws + 8388608 + 4194304);       //     65,536 B (2 x [32][512])
  u32* cnt  = (u32*)(ws + 8388608 + 4194304 + 65536);

  float* outHT  = out + 65536000;
  float* outCT  = out + 65552384;
  float* outAtt = out + 65568768;

  k_init<<<64, 256, 0, stream>>>(h0, hbuf + 16384, cnt);
  k_xp<<<dim3(16,16), 256, 0, stream>>>(xs, embW, Wih, bih, bhh, xpb);
  k_lstm<<<32, 256, 0, stream>>>(xpb, c0, Whh, feat, hbuf, cnt, outHT, outCT);
  k_attn<<<32, 256, 0, stream>>>(hs, feat, outAtt);
  k_logits<<<dim3(16,250), 256, 0, stream>>>(feat, affW, affb, out);
}